// Round 3
// baseline (32.709 us; speedup 1.0000x reference)
//
#include <hip/hip_runtime.h>

#define NSEQ 4096
#define DIM  256
#define WIN  128
#define BATCH 4

typedef __bf16 bf16x8 __attribute__((ext_vector_type(8)));
typedef float  f32x4  __attribute__((ext_vector_type(4)));

__device__ __forceinline__ unsigned short f2bf(float f) {
    unsigned u = __builtin_bit_cast(unsigned, f);
    u += 0x7fffu + ((u >> 16) & 1u);   // RNE
    return (unsigned short)(u >> 16);
}

// Swizzled subtiled layout for a 32x256 bf16 tile (8192 elements).
// subtile = (j>>2)*16 + (d>>4); 16B chunk = ((j&3)*2 + ((d>>3)&1)) ^ ((j>>2)&7).
// 8 consecutive d (aligned) stay contiguous & in order -> bf16x8 frag loads.
__device__ __forceinline__ int sub_off(int j, int d) {
    int subtile = ((j >> 2) << 4) + (d >> 4);
    int chunk   = (((j & 3) << 1) + ((d >> 3) & 1)) ^ ((j >> 2) & 7);
    return (subtile << 6) + (chunk << 3) + (d & 7);
}

// ---------------- pre-pass: f32 -> bf16, two layouts in ws ----------------
__global__ __launch_bounds__(256)
void cvt_kernel(const float* __restrict__ val,
                unsigned short* __restrict__ wsA,
                unsigned short* __restrict__ wsB) {
    __shared__ unsigned short A_l[8192];
    const int tile = blockIdx.x;                  // b*128 + tile_index
    const float* src = val + ((size_t)tile << 13);  // *32*256
    const int t = threadIdx.x;
    const int j = t >> 3;
    const int dbase = (t & 7) << 2;               // 0..28

    #pragma unroll
    for (int p = 0; p < 8; ++p) {
        const int d = dbase + (p << 5);
        float4 v = *reinterpret_cast<const float4*>(src + j * 256 + d);
        ushort4 h;
        h.x = f2bf(v.x); h.y = f2bf(v.y); h.z = f2bf(v.z); h.w = f2bf(v.w);
        *reinterpret_cast<ushort4*>(&A_l[sub_off(j, d)]) = h;
    }
    __syncthreads();

    // linear coalesced copy of layout A
    unsigned short* dstA = wsA + ((size_t)tile << 13);
    #pragma unroll
    for (int i = 0; i < 4; ++i) {
        uint4 x = *reinterpret_cast<const uint4*>(&A_l[(i << 11) + (t << 3)]);
        *reinterpret_cast<uint4*>(dstA + (i << 11) + (t << 3)) = x;
    }

    // build transposed layout B: element (j,d) at d*32 + slot*8 + (j&7),
    // slot = (j>>3) ^ ((d>>1)&3). Writes coalesced (chunk index c = d*4+slot = t+256i).
    unsigned short* dstB = wsB + ((size_t)tile << 13);
    #pragma unroll
    for (int i = 0; i < 4; ++i) {
        const int c = (i << 8) + t;
        const int d = c >> 2, sl = c & 3;
        const int j0 = (sl ^ ((d >> 1) & 3)) << 3;
        ushort4 lo, hi;
        lo.x = A_l[sub_off(j0 + 0, d)]; lo.y = A_l[sub_off(j0 + 1, d)];
        lo.z = A_l[sub_off(j0 + 2, d)]; lo.w = A_l[sub_off(j0 + 3, d)];
        hi.x = A_l[sub_off(j0 + 4, d)]; hi.y = A_l[sub_off(j0 + 5, d)];
        hi.z = A_l[sub_off(j0 + 6, d)]; hi.w = A_l[sub_off(j0 + 7, d)];
        *reinterpret_cast<ushort4*>(dstB + ((size_t)c << 3))     = lo;
        *reinterpret_cast<ushort4*>(dstB + ((size_t)c << 3) + 4) = hi;
    }
}

// ---------------- main kernel: scores + edges + PV, register-resident frags ----------------
__global__ __launch_bounds__(256, 2)
void sp_main(const unsigned short* __restrict__ wsA,
             const unsigned short* __restrict__ wsB,
             const float* __restrict__ state,
             float* __restrict__ out) {
    __shared__ unsigned short E_s[32 * 56];   // edges, row stride 56 (verified r1)
    __shared__ float ds_part[4][16];

    // XCD-aware swizzle: consecutive logical tiles share the j-window -> same XCD L2
    const int lbx = ((blockIdx.x & 7) << 6) + (blockIdx.x >> 3);   // bijective, 512 blocks
    const int b      = lbx >> 7;
    const int tile_i = lbx & 127;
    const int r0     = tile_i << 5;

    const int t   = threadIdx.x;
    const int w   = t >> 6;
    const int l   = t & 63;
    const int l15 = l & 15;
    const int l4  = l >> 4;
    const int mt  = w >> 1;            // score row-tile  (0..1)
    const int jt  = w & 1;             // score col-tile  (0..1)

    const unsigned short* baseA = wsA + ((size_t)b << 20);   // b*128*8192
    const unsigned short* baseB = wsB + ((size_t)b << 20);
    const float* stb  = state + ((size_t)b << 12);
    float* out_state  = out + ((size_t)b << 12);
    float* out_val    = out + ((size_t)BATCH * NSEQ) + (((size_t)b << 12) * DIM);

    // ---- A-fragments (Vi rows, fixed all loop): 8 x bf16x8 from global wsA ----
    const unsigned short* Ai = baseA + ((size_t)tile_i << 13);
    const int il = (mt << 4) + l15;
    const int jl = (jt << 4) + l15;
    bf16x8 af[8];
    #pragma unroll
    for (int ks = 0; ks < 8; ++ks)
        af[ks] = *reinterpret_cast<const bf16x8*>(Ai + sub_off(il, (l4 << 3) + (ks << 5)));

    const int tj0   = (tile_i >= 4) ? (tile_i - 4) : 0;
    const int ntile = tile_i - tj0 + 1;          // 1..5
    const int xd    = (l15 >> 1) & 3;            // PV slot xor (indep of tt)

    // ---- prefetch tile 0 fragments ----
    bf16x8 sb[8], pb[4];
    {
        const unsigned short* Bt = baseA + ((size_t)tj0 << 13);
        #pragma unroll
        for (int ks = 0; ks < 8; ++ks)
            sb[ks] = *reinterpret_cast<const bf16x8*>(Bt + sub_off(jl, (l4 << 3) + (ks << 5)));
        const unsigned short* Pt = baseB + ((size_t)tj0 << 13);
        #pragma unroll
        for (int tt = 0; tt < 4; ++tt) {
            const int d = (((w << 2) + tt) << 4) + l15;
            pb[tt] = *reinterpret_cast<const bf16x8*>(Pt + d * 32 + ((l4 ^ xd) << 3));
        }
    }

    float dsacc[4] = {0.f, 0.f, 0.f, 0.f};
    f32x4 accpv[2][4];
    #pragma unroll
    for (int m2 = 0; m2 < 2; ++m2)
        #pragma unroll
        for (int tt = 0; tt < 4; ++tt)
            accpv[m2][tt] = (f32x4){0.f, 0.f, 0.f, 0.f};

    for (int ti = 0; ti < ntile; ++ti) {
        const int jb = (tj0 + ti) << 5;
        const int jg = jb + jl;
        const float stv = stb[jg];

        // ---- scores: S(16x16 per wave) = Vi x Vj^T, K = 256 ----
        f32x4 acc = (f32x4){0.f, 0.f, 0.f, 0.f};
        #pragma unroll
        for (int ks = 0; ks < 8; ++ks)
            acc = __builtin_amdgcn_mfma_f32_16x16x32_bf16(af[ks], sb[ks], acc, 0, 0, 0);

        // prefetch next tile's score-B frags (WAR on sb is safe: MFMAs already issued)
        if (ti + 1 < ntile) {
            const unsigned short* Bn = baseA + ((size_t)(tj0 + ti + 1) << 13);
            #pragma unroll
            for (int ks = 0; ks < 8; ++ks)
                sb[ks] = *reinterpret_cast<const bf16x8*>(Bn + sub_off(jl, (l4 << 3) + (ks << 5)));
        }

        // ---- edges: scale, softsign, mask; accumulate delta_state; write E tile ----
        const int ib = r0 + (mt << 4) + (l4 << 2);
        #pragma unroll
        for (int r = 0; r < 4; ++r) {
            float s = acc[r] * 0.0625f;          // / sqrt(256)
            float e = s / (1.0f + fabsf(s));
            const int ig = ib + r;
            if (jg > ig || jg < ig - WIN) e = 0.0f;
            dsacc[r] += e * stv;
            E_s[((mt << 4) + (l4 << 2) + r) * 56 + (jt << 4) + l15] = f2bf(e);
        }
        __syncthreads();   // B: E ready

        // ---- PV: delta_val(32x256) += E(32x32) x Vj(32x256) ----
        bf16x8 ef0 = *reinterpret_cast<const bf16x8*>(&E_s[l15 * 56 + (l4 << 3)]);
        bf16x8 ef1 = *reinterpret_cast<const bf16x8*>(&E_s[(16 + l15) * 56 + (l4 << 3)]);
        #pragma unroll
        for (int tt = 0; tt < 4; ++tt) {
            accpv[0][tt] = __builtin_amdgcn_mfma_f32_16x16x32_bf16(ef0, pb[tt], accpv[0][tt], 0, 0, 0);
            accpv[1][tt] = __builtin_amdgcn_mfma_f32_16x16x32_bf16(ef1, pb[tt], accpv[1][tt], 0, 0, 0);
        }

        // prefetch next tile's PV-B frags
        if (ti + 1 < ntile) {
            const unsigned short* Pn = baseB + ((size_t)(tj0 + ti + 1) << 13);
            #pragma unroll
            for (int tt = 0; tt < 4; ++tt) {
                const int d = (((w << 2) + tt) << 4) + l15;
                pb[tt] = *reinterpret_cast<const bf16x8*>(Pn + d * 32 + ((l4 ^ xd) << 3));
            }
        }
        __syncthreads();   // C: protect E_s for next tile
    }

    // ---- delta_state: reduce over the 16 j-lanes, combine 2 col-half waves via LDS ----
    #pragma unroll
    for (int m = 1; m <= 8; m <<= 1) {
        #pragma unroll
        for (int r = 0; r < 4; ++r)
            dsacc[r] += __shfl_xor(dsacc[r], m, 64);
    }
    if (l15 == 0) {
        #pragma unroll
        for (int r = 0; r < 4; ++r)
            ds_part[w][(l4 << 2) + r] = dsacc[r];
    }
    __syncthreads();
    if (t < 32) {
        const int m2 = t >> 4;
        out_state[r0 + t] = ds_part[(m2 << 1)][t & 15] + ds_part[(m2 << 1) + 1][t & 15];
    }

    // ---- delta_val epilogue: C layout col=lane&15, row=(lane>>4)*4+r (verified) ----
    #pragma unroll
    for (int m2 = 0; m2 < 2; ++m2) {
        #pragma unroll
        for (int tt = 0; tt < 4; ++tt) {
            const int d = (w << 6) + (tt << 4) + l15;
            #pragma unroll
            for (int r = 0; r < 4; ++r) {
                const int ig = r0 + (m2 << 4) + (l4 << 2) + r;
                out_val[(size_t)ig * DIM + d] = accpv[m2][tt][r];
            }
        }
    }
}

extern "C" void kernel_launch(void* const* d_in, const int* in_sizes, int n_in,
                              void* d_out, int out_size, void* d_ws, size_t ws_size,
                              hipStream_t stream) {
    const float* val   = (const float*)d_in[0];
    const float* state = (const float*)d_in[1];
    float* out = (float*)d_out;
    unsigned short* wsA = (unsigned short*)d_ws;
    unsigned short* wsB = wsA + ((size_t)BATCH * 128 * 8192);   // +8.4 MB

    cvt_kernel<<<dim3(BATCH * 128), dim3(256), 0, stream>>>(val, wsA, wsB);
    sp_main<<<dim3(BATCH * 128), dim3(256), 0, stream>>>(wsA, wsB, state, out);
}

// Round 6
// 17.424 us; speedup vs baseline: 1.8772x; 1.8772x over previous
//
#include <hip/hip_runtime.h>

#define NSEQ 4096
#define DIM  256
#define WIN  128
#define BATCH 4

typedef __bf16 bf16x8 __attribute__((ext_vector_type(8)));
typedef float  f32x4  __attribute__((ext_vector_type(4)));
typedef int    v2i    __attribute__((ext_vector_type(2)));
typedef int    v4i    __attribute__((ext_vector_type(4)));

// subtiled layout: element (j,d) of a 32x256 tile at
// ((j>>2)*16 + (d>>4))*64 + (j&3)*16 + (d&15)  halfwords.
// Each 64-elem block = 4x16 row-major (rows j%4, cols d%16) = 128 B,
// exactly the block shape ds_read_b64_tr_b16 decodes.
__device__ __forceinline__ int sub_off(int j, int d) {
    return (((j >> 2) * 16 + (d >> 4)) << 6) + ((j & 3) << 4) + (d & 15);
}

__device__ __forceinline__ unsigned short f2bf(float f) {
    unsigned u = __builtin_bit_cast(unsigned, f);
    u += 0x7fffu + ((u >> 16) & 1u);   // RNE
    return (unsigned short)(u >> 16);
}

__global__ __launch_bounds__(256, 2)
void sp_kernel(const float* __restrict__ val,
               const float* __restrict__ state,
               float* __restrict__ out) {
    __shared__ __align__(128) unsigned short buf[2][8192];  // 32 KB double buffer
    __shared__ __align__(128) unsigned short E_s[32 * 56];  // 3.5 KB (verified layout)
    __shared__ float ds_part[4][16];

    // XCD-aware bijective swizzle (512 = 8*64): consecutive logical tiles -> same XCD L2
    const int bx  = blockIdx.x;
    const int lbx = ((bx & 7) << 6) + (bx >> 3);
    const int b      = lbx >> 7;
    const int tile_i = lbx & 127;
    const int r0     = tile_i << 5;

    const int t   = threadIdx.x;
    const int w   = t >> 6;
    const int l   = t & 63;
    const int l15 = l & 15;
    const int l4  = l >> 4;
    const int mt  = w >> 1;            // score row-tile (0..1)
    const int jt  = w & 1;             // score col-tile (0..1)

    const float* valb = val + ((size_t)b * NSEQ) * DIM;
    const float* stb  = state + ((size_t)b * NSEQ);
    float* out_state  = out + ((size_t)b * NSEQ);
    float* out_val    = out + (size_t)BATCH * NSEQ + ((size_t)b * NSEQ) * DIM;

    // staging index pattern (verified conflict-free in r2)
    const int s_jl[2] = {(w << 2) + l4, (w << 2) + l4 + 16};

    // ---- stage tile_i into buf[0] (serves as both A-source and first Vj tile) ----
    {
        const float* src = valb + ((size_t)tile_i << 13);
        #pragma unroll
        for (int p = 0; p < 8; ++p) {
            const int jl = s_jl[p & 1];
            const int d0 = (l15 << 2) + ((p >> 1) << 6);
            float4 v = *reinterpret_cast<const float4*>(src + jl * DIM + d0);
            ushort4 hh;
            hh.x = f2bf(v.x); hh.y = f2bf(v.y); hh.z = f2bf(v.z); hh.w = f2bf(v.w);
            *reinterpret_cast<ushort4*>(&buf[0][sub_off(jl, d0)]) = hh;
        }
    }
    __syncthreads();

    // ---- A-fragments (Vi rows), registers for whole loop ----
    const int il = (mt << 4) + l15;
    const int jl = (jt << 4) + l15;
    bf16x8 af[8];
    #pragma unroll
    for (int ks = 0; ks < 8; ++ks)
        af[ks] = *reinterpret_cast<const bf16x8*>(&buf[0][sub_off(il, (l4 << 3) + (ks << 5))]);

    const int tj0 = (tile_i >= 4) ? (tile_i - 4) : 0;

    float dsacc[4] = {0.f, 0.f, 0.f, 0.f};
    f32x4 accpv[2][4];
    #pragma unroll
    for (int m2 = 0; m2 < 2; ++m2)
        #pragma unroll
        for (int tt = 0; tt < 4; ++tt)
            accpv[m2][tt] = (f32x4){0.f, 0.f, 0.f, 0.f};

    int p = 0;
    for (int ti = tile_i; ti >= tj0; --ti) {
        const unsigned short* bp = &buf[p][0];
        const bool havenext = (ti > tj0);

        // ---- T14 split: ISSUE next tile's global loads now (consume later) ----
        float4 stg[8];
        if (havenext) {
            const float* src = valb + ((size_t)(ti - 1) << 13);
            #pragma unroll
            for (int q = 0; q < 8; ++q)
                stg[q] = *reinterpret_cast<const float4*>(src + s_jl[q & 1] * DIM
                                                          + (l15 << 2) + ((q >> 1) << 6));
        }

        // ---- scores: S(16x16 per wave) = Vi x Vj^T, K=256 ----
        bf16x8 sb[8];
        #pragma unroll
        for (int ks = 0; ks < 8; ++ks)
            sb[ks] = *reinterpret_cast<const bf16x8*>(&bp[sub_off(jl, (l4 << 3) + (ks << 5))]);
        f32x4 acc = (f32x4){0.f, 0.f, 0.f, 0.f};
        __builtin_amdgcn_s_setprio(1);
        #pragma unroll
        for (int ks = 0; ks < 8; ++ks)
            acc = __builtin_amdgcn_mfma_f32_16x16x32_bf16(af[ks], sb[ks], acc, 0, 0, 0);
        __builtin_amdgcn_s_setprio(0);

        // ---- edges: scale, softsign, mask; delta_state accum; E tile write ----
        const int jb = ti << 5;
        const int jg = jb + jl;
        const float stv = stb[jg];
        const int ib = r0 + (mt << 4) + (l4 << 2);
        #pragma unroll
        for (int r = 0; r < 4; ++r) {
            float s = acc[r] * 0.0625f;          // / sqrt(256)
            float e = s / (1.0f + fabsf(s));
            const int ig = ib + r;
            if (jg > ig || jg < ig - WIN) e = 0.0f;
            dsacc[r] += e * stv;
            E_s[((mt << 4) + (l4 << 2) + r) * 56 + (jt << 4) + l15] = f2bf(e);
        }

        // ---- T14 split: convert + LDS-write the prefetched tile ----
        if (havenext) {
            unsigned short* bn = &buf[1 - p][0];
            #pragma unroll
            for (int q = 0; q < 8; ++q) {
                ushort4 hh;
                hh.x = f2bf(stg[q].x); hh.y = f2bf(stg[q].y);
                hh.z = f2bf(stg[q].z); hh.w = f2bf(stg[q].w);
                *reinterpret_cast<ushort4*>(&bn[sub_off(s_jl[q & 1],
                                                        (l15 << 2) + ((q >> 1) << 6))]) = hh;
            }
        }
        __syncthreads();   // E ready; staged tile visible; prev-iter readers long done

        // ---- PV: delta_val(32x256) += E(32x32) x Vj(32x256); wave owns d [64w,64w+64) ----
        bf16x8 ef0 = *reinterpret_cast<const bf16x8*>(&E_s[l15 * 56 + (l4 << 3)]);
        bf16x8 ef1 = *reinterpret_cast<const bf16x8*>(&E_s[(16 + l15) * 56 + (l4 << 3)]);
        const unsigned lds_base = (unsigned)(size_t)bp;
        #pragma unroll
        for (int tt = 0; tt < 4; ++tt) {
            const int nt = (w << 2) + tt;        // d-subtile 0..15
            // corrected tr-read addressing: 8-byte slot granularity -> column = (addr>>3)&15
            unsigned a0 = lds_base + (unsigned)((((l4 << 5) + nt) << 7) + (l15 << 3));
            v2i t0, t1;
            asm volatile("ds_read_b64_tr_b16 %0, %1" : "=v"(t0) : "v"(a0) : "memory");
            asm volatile("ds_read_b64_tr_b16 %0, %1 offset:2048" : "=v"(t1) : "v"(a0) : "memory");
            asm volatile("s_waitcnt lgkmcnt(0)" ::: "memory");
            __builtin_amdgcn_sched_barrier(0);
            v4i tmp; tmp.x = t0.x; tmp.y = t0.y; tmp.z = t1.x; tmp.w = t1.y;
            bf16x8 bfr = __builtin_bit_cast(bf16x8, tmp);
            __builtin_amdgcn_s_setprio(1);
            accpv[0][tt] = __builtin_amdgcn_mfma_f32_16x16x32_bf16(ef0, bfr, accpv[0][tt], 0, 0, 0);
            accpv[1][tt] = __builtin_amdgcn_mfma_f32_16x16x32_bf16(ef1, bfr, accpv[1][tt], 0, 0, 0);
            __builtin_amdgcn_s_setprio(0);
        }
        if (havenext) __syncthreads();   // PV reads of buf[p] done before it's re-staged
        p ^= 1;
    }

    // ---- delta_state: shuffle-reduce 16 j-lanes, combine jt-halves via LDS ----
    #pragma unroll
    for (int m = 1; m <= 8; m <<= 1) {
        #pragma unroll
        for (int r = 0; r < 4; ++r)
            dsacc[r] += __shfl_xor(dsacc[r], m, 64);
    }
    if (l15 == 0) {
        #pragma unroll
        for (int r = 0; r < 4; ++r)
            ds_part[w][(l4 << 2) + r] = dsacc[r];
    }
    __syncthreads();
    if (t < 32) {
        const int m2 = t >> 4;
        out_state[r0 + t] = ds_part[(m2 << 1)][t & 15] + ds_part[(m2 << 1) + 1][t & 15];
    }

    // ---- delta_val epilogue: C layout col=lane&15, row=(lane>>4)*4+r (verified) ----
    #pragma unroll
    for (int m2 = 0; m2 < 2; ++m2) {
        #pragma unroll
        for (int tt = 0; tt < 4; ++tt) {
            const int d = (w << 6) + (tt << 4) + l15;
            #pragma unroll
            for (int r = 0; r < 4; ++r) {
                const int ig = r0 + (m2 << 4) + (l4 << 2) + r;
                out_val[(size_t)ig * DIM + d] = accpv[m2][tt][r];
            }
        }
    }
}

extern "C" void kernel_launch(void* const* d_in, const int* in_sizes, int n_in,
                              void* d_out, int out_size, void* d_ws, size_t ws_size,
                              hipStream_t stream) {
    const float* val   = (const float*)d_in[0];
    const float* state = (const float*)d_in[1];
    float* out = (float*)d_out;
    sp_kernel<<<dim3(BATCH * (NSEQ / 32)), dim3(256), 0, stream>>>(val, state, out);
}

// Round 7
// 17.202 us; speedup vs baseline: 1.9014x; 1.0129x over previous
//
#include <hip/hip_runtime.h>

#define NSEQ 4096
#define DIM  256
#define WIN  128
#define BATCH 4

typedef __bf16 bf16x8 __attribute__((ext_vector_type(8)));
typedef float  f32x4  __attribute__((ext_vector_type(4)));
typedef int    v2i    __attribute__((ext_vector_type(2)));
typedef int    v4i    __attribute__((ext_vector_type(4)));

// subtiled layout: element (j,d) of a 32x256 tile at
// ((j>>2)*16 + (d>>4))*64 + (j&3)*16 + (d&15)  halfwords.
// Each 64-elem block = 4x16 row-major = 128 B, the tr_b16 decode shape.
__device__ __forceinline__ int sub_off(int j, int d) {
    return (((j >> 2) * 16 + (d >> 4)) << 6) + ((j & 3) << 4) + (d & 15);
}

__device__ __forceinline__ unsigned short f2bf(float f) {
    unsigned u = __builtin_bit_cast(unsigned, f);
    u += 0x7fffu + ((u >> 16) & 1u);   // RNE
    return (unsigned short)(u >> 16);
}

__global__ __launch_bounds__(256, 2)
void sp_kernel(const float* __restrict__ val,
               const float* __restrict__ state,
               float* __restrict__ out) {
    __shared__ __align__(128) unsigned short vbuf[3][8192];   // 48 KB ring
    __shared__ __align__(128) unsigned short E_s[2][32 * 56]; // 7 KB parity dbuf
    __shared__ float ds_part[4][16];

    // XCD-aware bijective swizzle (512 = 8*64)
    const int bx  = blockIdx.x;
    const int lbx = ((bx & 7) << 6) + (bx >> 3);
    const int b      = lbx >> 7;
    const int tile_i = lbx & 127;
    const int r0     = tile_i << 5;

    const int t   = threadIdx.x;
    const int w   = t >> 6;
    const int l   = t & 63;
    const int l15 = l & 15;
    const int l4  = l >> 4;
    const int mt  = w >> 1;            // score row-tile (0..1)
    const int jt  = w & 1;             // score col-tile (0..1)

    const float* valb = val + ((size_t)b * NSEQ) * DIM;
    const float* stb  = state + ((size_t)b * NSEQ);
    float* out_state  = out + ((size_t)b * NSEQ);
    float* out_val    = out + (size_t)BATCH * NSEQ + ((size_t)b * NSEQ) * DIM;

    // staging index pattern (verified conflict-free)
    const int s_jl[2] = {(w << 2) + l4, (w << 2) + l4 + 16};

    // ---- prologue: stage tile_i into vbuf[0] ----
    {
        const float* src = valb + ((size_t)tile_i << 13);
        #pragma unroll
        for (int p = 0; p < 8; ++p) {
            const int jl = s_jl[p & 1];
            const int d0 = (l15 << 2) + ((p >> 1) << 6);
            float4 v = *reinterpret_cast<const float4*>(src + jl * DIM + d0);
            ushort4 hh;
            hh.x = f2bf(v.x); hh.y = f2bf(v.y); hh.z = f2bf(v.z); hh.w = f2bf(v.w);
            *reinterpret_cast<ushort4*>(&vbuf[0][sub_off(jl, d0)]) = hh;
        }
    }
    __syncthreads();

    // ---- A-fragments (Vi rows) + first score-B frags, both from vbuf[0] ----
    const int il = (mt << 4) + l15;
    const int jl = (jt << 4) + l15;
    bf16x8 af[8], sb[8];
    #pragma unroll
    for (int ks = 0; ks < 8; ++ks) {
        af[ks] = *reinterpret_cast<const bf16x8*>(&vbuf[0][sub_off(il, (l4 << 3) + (ks << 5))]);
        sb[ks] = *reinterpret_cast<const bf16x8*>(&vbuf[0][sub_off(jl, (l4 << 3) + (ks << 5))]);
    }

    const int tj0   = (tile_i >= 4) ? (tile_i - 4) : 0;
    const int ntile = tile_i - tj0 + 1;

    float dsacc[4] = {0.f, 0.f, 0.f, 0.f};
    f32x4 accpv[2][4];
    #pragma unroll
    for (int m2 = 0; m2 < 2; ++m2)
        #pragma unroll
        for (int tt = 0; tt < 4; ++tt)
            accpv[m2][tt] = (f32x4){0.f, 0.f, 0.f, 0.f};

    int bpi = 0;
    for (int q = 0; q < ntile; ++q) {
        const int ti = tile_i - q;
        const bool havenext = (q + 1 < ntile);
        const int bni = (bpi == 2) ? 0 : bpi + 1;
        const unsigned short* bp = &vbuf[bpi][0];
        unsigned short* bn = &vbuf[bni][0];
        unsigned short* Ecur = &E_s[q & 1][0];

        // ---- issue next-tile global loads + state load early (latency hides under MFMA) ----
        const int jg = (ti << 5) + jl;
        const float stv = stb[jg];
        float4 stg[8];
        if (havenext) {
            const float* src = valb + ((size_t)(ti - 1) << 13);
            #pragma unroll
            for (int qq = 0; qq < 8; ++qq)
                stg[qq] = *reinterpret_cast<const float4*>(src + s_jl[qq & 1] * DIM
                                                           + (l15 << 2) + ((qq >> 1) << 6));
        }

        // ---- scores: S(16x16 per wave) = Vi x Vj^T, K=256 ----
        f32x4 acc = (f32x4){0.f, 0.f, 0.f, 0.f};
        __builtin_amdgcn_s_setprio(1);
        #pragma unroll
        for (int ks = 0; ks < 8; ++ks)
            acc = __builtin_amdgcn_mfma_f32_16x16x32_bf16(af[ks], sb[ks], acc, 0, 0, 0);
        __builtin_amdgcn_s_setprio(0);

        // ---- edges: scale, softsign, mask; delta_state accum; E write ----
        const int ib = r0 + (mt << 4) + (l4 << 2);
        #pragma unroll
        for (int r = 0; r < 4; ++r) {
            float s = acc[r] * 0.0625f;          // / sqrt(256)
            float e = s / (1.0f + fabsf(s));
            const int ig = ib + r;
            if (jg > ig || jg < ig - WIN) e = 0.0f;
            dsacc[r] += e * stv;
            Ecur[((mt << 4) + (l4 << 2) + r) * 56 + (jt << 4) + l15] = f2bf(e);
        }

        // ---- convert + LDS-write the prefetched tile into ring slot bn ----
        if (havenext) {
            #pragma unroll
            for (int qq = 0; qq < 8; ++qq) {
                ushort4 hh;
                hh.x = f2bf(stg[qq].x); hh.y = f2bf(stg[qq].y);
                hh.z = f2bf(stg[qq].z); hh.w = f2bf(stg[qq].w);
                *reinterpret_cast<ushort4*>(&bn[sub_off(s_jl[qq & 1],
                                                        (l15 << 2) + ((qq >> 1) << 6))]) = hh;
            }
        }
        __syncthreads();   // the single per-iteration barrier

        // ---- post-barrier: E frags, next-tile sb (overlapped), batched tr_reads, PV MFMA ----
        bf16x8 ef0 = *reinterpret_cast<const bf16x8*>(&Ecur[l15 * 56 + (l4 << 3)]);
        bf16x8 ef1 = *reinterpret_cast<const bf16x8*>(&Ecur[(16 + l15) * 56 + (l4 << 3)]);
        if (havenext) {
            #pragma unroll
            for (int ks = 0; ks < 8; ++ks)
                sb[ks] = *reinterpret_cast<const bf16x8*>(&bn[sub_off(jl, (l4 << 3) + (ks << 5))]);
        }
        const unsigned lds_base = (unsigned)(size_t)bp;
        v2i tr[8];
        #pragma unroll
        for (int tt = 0; tt < 4; ++tt) {
            const int nt = (w << 2) + tt;
            unsigned a0 = lds_base + (unsigned)((((l4 << 5) + nt) << 7) + (l15 << 3));
            asm volatile("ds_read_b64_tr_b16 %0, %1" : "=v"(tr[2 * tt]) : "v"(a0) : "memory");
            asm volatile("ds_read_b64_tr_b16 %0, %1 offset:2048" : "=v"(tr[2 * tt + 1]) : "v"(a0) : "memory");
        }
        asm volatile("s_waitcnt lgkmcnt(0)" ::: "memory");
        __builtin_amdgcn_sched_barrier(0);
        __builtin_amdgcn_s_setprio(1);
        #pragma unroll
        for (int tt = 0; tt < 4; ++tt) {
            v4i tmp;
            tmp.x = tr[2 * tt].x; tmp.y = tr[2 * tt].y;
            tmp.z = tr[2 * tt + 1].x; tmp.w = tr[2 * tt + 1].y;
            bf16x8 bfr = __builtin_bit_cast(bf16x8, tmp);
            accpv[0][tt] = __builtin_amdgcn_mfma_f32_16x16x32_bf16(ef0, bfr, accpv[0][tt], 0, 0, 0);
            accpv[1][tt] = __builtin_amdgcn_mfma_f32_16x16x32_bf16(ef1, bfr, accpv[1][tt], 0, 0, 0);
        }
        __builtin_amdgcn_s_setprio(0);
        bpi = bni;
    }

    // ---- delta_state: shuffle-reduce 16 j-lanes, combine jt-halves via LDS ----
    #pragma unroll
    for (int m = 1; m <= 8; m <<= 1) {
        #pragma unroll
        for (int r = 0; r < 4; ++r)
            dsacc[r] += __shfl_xor(dsacc[r], m, 64);
    }
    if (l15 == 0) {
        #pragma unroll
        for (int r = 0; r < 4; ++r)
            ds_part[w][(l4 << 2) + r] = dsacc[r];
    }
    __syncthreads();
    if (t < 32) {
        const int m2 = t >> 4;
        out_state[r0 + t] = ds_part[(m2 << 1)][t & 15] + ds_part[(m2 << 1) + 1][t & 15];
    }

    // ---- delta_val epilogue: C layout col=lane&15, row=(lane>>4)*4+r (verified) ----
    #pragma unroll
    for (int m2 = 0; m2 < 2; ++m2) {
        #pragma unroll
        for (int tt = 0; tt < 4; ++tt) {
            const int d = (w << 6) + (tt << 4) + l15;
            #pragma unroll
            for (int r = 0; r < 4; ++r) {
                const int ig = r0 + (m2 << 4) + (l4 << 2) + r;
                out_val[(size_t)ig * DIM + d] = accpv[m2][tt][r];
            }
        }
    }
}

extern "C" void kernel_launch(void* const* d_in, const int* in_sizes, int n_in,
                              void* d_out, int out_size, void* d_ws, size_t ws_size,
                              hipStream_t stream) {
    const float* val   = (const float*)d_in[0];
    const float* state = (const float*)d_in[1];
    float* out = (float*)d_out;
    sp_kernel<<<dim3(BATCH * (NSEQ / 32)), dim3(256), 0, stream>>>(val, state, out);
}

// Round 8
// 16.979 us; speedup vs baseline: 1.9265x; 1.0132x over previous
//
#include <hip/hip_runtime.h>

#define NSEQ 4096
#define DIM  256
#define WIN  128
#define BATCH 4

typedef __bf16 bf16x8 __attribute__((ext_vector_type(8)));
typedef float  f32x4  __attribute__((ext_vector_type(4)));
typedef int    v2i    __attribute__((ext_vector_type(2)));
typedef int    v4i    __attribute__((ext_vector_type(4)));

// subtiled layout: element (j,d) of a 32x256 tile at
// ((j>>2)*16 + (d>>4))*64 + (j&3)*16 + (d&15)  halfwords. (verified r2/r6)
__device__ __forceinline__ int sub_off(int j, int d) {
    return (((j >> 2) * 16 + (d >> 4)) << 6) + ((j & 3) << 4) + (d & 15);
}

__device__ __forceinline__ unsigned short f2bf(float f) {
    unsigned u = __builtin_bit_cast(unsigned, f);
    u += 0x7fffu + ((u >> 16) & 1u);   // RNE
    return (unsigned short)(u >> 16);
}

// HW packed f32->bf16 (RNE), 2 elements per instruction
__device__ __forceinline__ unsigned pk2bf(float lo, float hi) {
    unsigned r;
    asm("v_cvt_pk_bf16_f32 %0, %1, %2" : "=v"(r) : "v"(lo), "v"(hi));
    return r;
}

__device__ __forceinline__ void issue_loads(const float* __restrict__ src,
                                            const int s_jl0, const int s_jl1,
                                            const int l15, float4 (&dst)[8]) {
    #pragma unroll
    for (int qq = 0; qq < 8; ++qq)
        dst[qq] = *reinterpret_cast<const float4*>(src + (qq & 1 ? s_jl1 : s_jl0) * DIM
                                                   + (l15 << 2) + ((qq >> 1) << 6));
}

__device__ __forceinline__ void stage_write(unsigned short* __restrict__ bn,
                                            const int s_jl0, const int s_jl1,
                                            const int l15, const float4 (&stg)[8]) {
    #pragma unroll
    for (int qq = 0; qq < 8; ++qq) {
        uint2 u;
        u.x = pk2bf(stg[qq].x, stg[qq].y);
        u.y = pk2bf(stg[qq].z, stg[qq].w);
        *reinterpret_cast<uint2*>(&bn[sub_off(qq & 1 ? s_jl1 : s_jl0,
                                              (l15 << 2) + ((qq >> 1) << 6))]) = u;
    }
}

__global__ __launch_bounds__(256, 2)
void sp_kernel(const float* __restrict__ val,
               const float* __restrict__ state,
               float* __restrict__ out) {
    __shared__ __align__(128) unsigned short vbuf[3][8192];   // 48 KB ring
    __shared__ __align__(128) unsigned short E_s[2][32 * 56]; // 7 KB parity dbuf
    __shared__ float ds_part[4][16];

    // XCD-aware bijective swizzle (512 = 8*64)
    const int bx  = blockIdx.x;
    const int lbx = ((bx & 7) << 6) + (bx >> 3);
    const int b      = lbx >> 7;
    const int tile_i = lbx & 127;
    const int r0     = tile_i << 5;

    const int t   = threadIdx.x;
    const int w   = t >> 6;
    const int l   = t & 63;
    const int l15 = l & 15;
    const int l4  = l >> 4;
    const int mt  = w >> 1;            // score row-tile (0..1)
    const int jt  = w & 1;             // score col-tile (0..1)

    const float* valb = val + ((size_t)b * NSEQ) * DIM;
    const float* stb  = state + ((size_t)b * NSEQ);
    float* out_state  = out + ((size_t)b * NSEQ);
    float* out_val    = out + (size_t)BATCH * NSEQ + ((size_t)b * NSEQ) * DIM;

    // staging row pattern (verified conflict-free)
    const int s_jl0 = (w << 2) + l4;
    const int s_jl1 = s_jl0 + 16;

    const int tj0   = (tile_i >= 4) ? (tile_i - 4) : 0;
    const int ntile = tile_i - tj0 + 1;

    float4 stgA[8], stgB[8];

    // ---- prologue: stage tile_i into vbuf[0]; issue tile_i-1 loads into setB ----
    {
        float4 pv[8];
        issue_loads(valb + ((size_t)tile_i << 13), s_jl0, s_jl1, l15, pv);
        if (ntile > 1)
            issue_loads(valb + ((size_t)(tile_i - 1) << 13), s_jl0, s_jl1, l15, stgB);
        stage_write(&vbuf[0][0], s_jl0, s_jl1, l15, pv);
    }
    __syncthreads();

    // ---- A-fragments (Vi rows) + first score-B frags, both from vbuf[0] ----
    const int il = (mt << 4) + l15;
    const int jl = (jt << 4) + l15;
    bf16x8 af[8], sb[8];
    #pragma unroll
    for (int ks = 0; ks < 8; ++ks) {
        af[ks] = *reinterpret_cast<const bf16x8*>(&vbuf[0][sub_off(il, (l4 << 3) + (ks << 5))]);
        sb[ks] = *reinterpret_cast<const bf16x8*>(&vbuf[0][sub_off(jl, (l4 << 3) + (ks << 5))]);
    }

    float dsacc[4] = {0.f, 0.f, 0.f, 0.f};
    f32x4 accpv[2][4];
    #pragma unroll
    for (int m2 = 0; m2 < 2; ++m2)
        #pragma unroll
        for (int tt = 0; tt < 4; ++tt)
            accpv[m2][tt] = (f32x4){0.f, 0.f, 0.f, 0.f};

    // ---- main loop, fully unrolled (<=5 iters, block-uniform break) ----
    #pragma unroll
    for (int q = 0; q < 5; ++q) {
        if (q >= ntile) break;
        const int ti  = tile_i - q;
        const int cs  = q % 3;             // compile-time per unrolled copy
        const int ns  = (q + 1) % 3;
        const unsigned short* bp = &vbuf[cs][0];
        unsigned short* bn = &vbuf[ns][0];
        unsigned short* Ecur = &E_s[q & 1][0];

        const int jg = (ti << 5) + jl;
        const float stv = stb[jg];

        // issue tile q+2 loads into the set freed this iteration (distance-2)
        if (q + 2 < ntile) {
            if ((q & 1) == 0)
                issue_loads(valb + ((size_t)(ti - 2) << 13), s_jl0, s_jl1, l15, stgA);
            else
                issue_loads(valb + ((size_t)(ti - 2) << 13), s_jl0, s_jl1, l15, stgB);
        }

        // ---- scores: S(16x16 per wave) = Vi x Vj^T, K=256 ----
        f32x4 acc = (f32x4){0.f, 0.f, 0.f, 0.f};
        __builtin_amdgcn_s_setprio(1);
        #pragma unroll
        for (int ks = 0; ks < 8; ++ks)
            acc = __builtin_amdgcn_mfma_f32_16x16x32_bf16(af[ks], sb[ks], acc, 0, 0, 0);
        __builtin_amdgcn_s_setprio(0);

        // ---- edges: scale, softsign (fast rcp), mask; dsacc; E write ----
        const int ib = r0 + (mt << 4) + (l4 << 2);
        #pragma unroll
        for (int r = 0; r < 4; ++r) {
            float s = acc[r] * 0.0625f;      // / sqrt(256)
            float e = s * __builtin_amdgcn_rcpf(1.0f + fabsf(s));
            const int ig = ib + r;
            if (jg > ig || jg < ig - WIN) e = 0.0f;
            dsacc[r] += e * stv;
            Ecur[((mt << 4) + (l4 << 2) + r) * 56 + (jt << 4) + l15] = f2bf(e);
        }

        // ---- stage-write tile q+1 (loaded one full iteration ago) ----
        if (q + 1 < ntile) {
            if ((q & 1) == 0)
                stage_write(bn, s_jl0, s_jl1, l15, stgB);
            else
                stage_write(bn, s_jl0, s_jl1, l15, stgA);
        }
        __syncthreads();   // single per-iteration barrier

        // ---- post-barrier: E frags, next sb (overlapped), batched tr_reads, PV ----
        bf16x8 ef0 = *reinterpret_cast<const bf16x8*>(&Ecur[l15 * 56 + (l4 << 3)]);
        bf16x8 ef1 = *reinterpret_cast<const bf16x8*>(&Ecur[(16 + l15) * 56 + (l4 << 3)]);
        if (q + 1 < ntile) {
            #pragma unroll
            for (int ks = 0; ks < 8; ++ks)
                sb[ks] = *reinterpret_cast<const bf16x8*>(&bn[sub_off(jl, (l4 << 3) + (ks << 5))]);
        }
        const unsigned lds_base = (unsigned)(size_t)bp;
        v2i tr[8];
        #pragma unroll
        for (int tt = 0; tt < 4; ++tt) {
            const int nt = (w << 2) + tt;
            unsigned a0 = lds_base + (unsigned)((((l4 << 5) + nt) << 7) + (l15 << 3));
            asm volatile("ds_read_b64_tr_b16 %0, %1" : "=v"(tr[2 * tt]) : "v"(a0) : "memory");
            asm volatile("ds_read_b64_tr_b16 %0, %1 offset:2048" : "=v"(tr[2 * tt + 1]) : "v"(a0) : "memory");
        }
        asm volatile("s_waitcnt lgkmcnt(0)" ::: "memory");
        __builtin_amdgcn_sched_barrier(0);
        __builtin_amdgcn_s_setprio(1);
        #pragma unroll
        for (int tt = 0; tt < 4; ++tt) {
            v4i tmp;
            tmp.x = tr[2 * tt].x;     tmp.y = tr[2 * tt].y;
            tmp.z = tr[2 * tt + 1].x; tmp.w = tr[2 * tt + 1].y;
            bf16x8 bfr = __builtin_bit_cast(bf16x8, tmp);
            accpv[0][tt] = __builtin_amdgcn_mfma_f32_16x16x32_bf16(ef0, bfr, accpv[0][tt], 0, 0, 0);
            accpv[1][tt] = __builtin_amdgcn_mfma_f32_16x16x32_bf16(ef1, bfr, accpv[1][tt], 0, 0, 0);
        }
        __builtin_amdgcn_s_setprio(0);
    }

    // ---- delta_state: shuffle-reduce 16 j-lanes, combine jt-halves via LDS ----
    #pragma unroll
    for (int m = 1; m <= 8; m <<= 1) {
        #pragma unroll
        for (int r = 0; r < 4; ++r)
            dsacc[r] += __shfl_xor(dsacc[r], m, 64);
    }
    if (l15 == 0) {
        #pragma unroll
        for (int r = 0; r < 4; ++r)
            ds_part[w][(l4 << 2) + r] = dsacc[r];
    }
    __syncthreads();
    if (t < 32) {
        const int m2 = t >> 4;
        out_state[r0 + t] = ds_part[(m2 << 1)][t & 15] + ds_part[(m2 << 1) + 1][t & 15];
    }

    // ---- delta_val epilogue: C layout col=lane&15, row=(lane>>4)*4+r (verified) ----
    #pragma unroll
    for (int m2 = 0; m2 < 2; ++m2) {
        #pragma unroll
        for (int tt = 0; tt < 4; ++tt) {
            const int d = (w << 6) + (tt << 4) + l15;
            #pragma unroll
            for (int r = 0; r < 4; ++r) {
                const int ig = r0 + (m2 << 4) + (l4 << 2) + r;
                out_val[(size_t)ig * DIM + d] = accpv[m2][tt][r];
            }
        }
    }
}

extern "C" void kernel_launch(void* const* d_in, const int* in_sizes, int n_in,
                              void* d_out, int out_size, void* d_ws, size_t ws_size,
                              hipStream_t stream) {
    const float* val   = (const float*)d_in[0];
    const float* state = (const float*)d_in[1];
    float* out = (float*)d_out;
    sp_kernel<<<dim3(BATCH * (NSEQ / 32)), dim3(256), 0, stream>>>(val, state, out);
}